// Round 1
// baseline (34.426 us; speedup 1.0000x reference)
//
#include <hip/hip_runtime.h>

// out[b][l] = x[b][perm[b][l]]  — per-row pseudo-random interleave.
// B=1024 rows, L=16384 elements/row (fp32). Row = 64 KiB -> stage in LDS,
// gather from LDS, all global traffic fully coalesced via float4/int4.

constexpr int L = 16384;
constexpr int BLOCK = 256;
constexpr int VEC_PER_THREAD = L / 4 / BLOCK;  // 16 float4 per thread

__global__ __launch_bounds__(BLOCK) void interleave_kernel(
    const float* __restrict__ x,
    const int* __restrict__ perm,
    float* __restrict__ out) {
  extern __shared__ float row[];  // 16384 floats = 64 KiB

  const long long base = (long long)blockIdx.x * L;
  const float4* __restrict__ x4 = reinterpret_cast<const float4*>(x + base);
  float4* __restrict__ row4 = reinterpret_cast<float4*>(row);

  // Stage the row into LDS, coalesced 16 B/lane.
#pragma unroll
  for (int i = 0; i < VEC_PER_THREAD; ++i) {
    const int idx = threadIdx.x + i * BLOCK;
    row4[idx] = x4[idx];
  }
  __syncthreads();

  const int4* __restrict__ p4 = reinterpret_cast<const int4*>(perm + base);
  float4* __restrict__ o4 = reinterpret_cast<float4*>(out + base);

#pragma unroll
  for (int i = 0; i < VEC_PER_THREAD; ++i) {
    const int idx = threadIdx.x + i * BLOCK;
    const int4 p = p4[idx];
    float4 v;
    v.x = row[p.x];
    v.y = row[p.y];
    v.z = row[p.z];
    v.w = row[p.w];
    o4[idx] = v;
  }
}

extern "C" void kernel_launch(void* const* d_in, const int* in_sizes, int n_in,
                              void* d_out, int out_size, void* d_ws, size_t ws_size,
                              hipStream_t stream) {
  const float* x = (const float*)d_in[0];
  const int* perm = (const int*)d_in[1];
  float* out = (float*)d_out;

  const int B = out_size / L;  // 1024
  interleave_kernel<<<B, BLOCK, L * sizeof(float), stream>>>(x, perm, out);
}